// Round 6
// baseline (360.123 us; speedup 1.0000x reference)
//
#include <hip/hip_runtime.h>
#include <cstdint>
#include <cstddef>

// Problem constants (B=4, L=1024)
#define DM 1024      // D_MODEL
#define EI 2048      // E_INNER
#define NS 16        // N_STATE
#define DR 64        // DT_RANK
#define BB 4
#define LL 1024
#define MM (BB*LL)   // 4096 token rows
#define NCHUNK 64
#define CHUNK 16

typedef __attribute__((ext_vector_type(8))) __bf16 bf16x8;
typedef __attribute__((ext_vector_type(4))) float f32x4;
typedef __attribute__((ext_vector_type(8))) unsigned short u16x8;

__device__ __forceinline__ unsigned short f2bf(float f) {
    union { float f; unsigned int u; } v; v.f = f;
    unsigned int r = v.u + 0x7FFFu + ((v.u >> 16) & 1u);   // RNE
    return (unsigned short)(r >> 16);
}
__device__ __forceinline__ float bf2f(unsigned short u) {
    union { unsigned int u; float f; } v; v.u = ((unsigned int)u) << 16;
    return v.f;
}

__device__ __forceinline__ void gload_lds16(const unsigned short* g, unsigned short* l) {
    __builtin_amdgcn_global_load_lds(
        (const __attribute__((address_space(1))) unsigned int*)g,
        (__attribute__((address_space(3))) unsigned int*)l, 16, 0, 0);
}

// ---------------- fused pre-pass: 4 weight transposes + RMSNorm, one launch ----------------
__global__ void pre_all(const float* __restrict__ W_in, const float* __restrict__ W_x,
                        const float* __restrict__ W_dt, const float* __restrict__ W_out,
                        const float* __restrict__ x, const float* __restrict__ nw,
                        unsigned short* __restrict__ wt_in, unsigned short* __restrict__ wt_x,
                        unsigned short* __restrict__ wt_dt, unsigned short* __restrict__ wt_out,
                        unsigned short* __restrict__ xnorm) {
    int id = blockIdx.x;
    int tx = threadIdx.x, ty = threadIdx.y;
    if (id >= 6528) {   // ---- rmsnorm ----
        int m = id - 6528, tid = ty * 32 + tx;
        const float4* row = (const float4*)(x + (size_t)m * DM);
        float4 v = row[tid];
        float ss = v.x*v.x + v.y*v.y + v.z*v.z + v.w*v.w;
        #pragma unroll
        for (int o = 32; o; o >>= 1) ss += __shfl_down(ss, o);
        __shared__ float red[4];
        if ((tid & 63) == 0) red[tid >> 6] = ss;
        __syncthreads();
        ss = red[0] + red[1] + red[2] + red[3];
        float scale = rsqrtf(ss * (1.0f / DM) + 1e-6f);
        float4 wv = ((const float4*)nw)[tid];
        ushort4 o4;
        o4.x = f2bf(v.x * scale * wv.x);
        o4.y = f2bf(v.y * scale * wv.y);
        o4.z = f2bf(v.z * scale * wv.z);
        o4.w = f2bf(v.w * scale * wv.w);
        ((ushort4*)xnorm)[(size_t)m * (DM/4) + tid] = o4;
        return;
    }
    // ---- transpose fp32 (R,C) -> bf16 (Cpad,R) ----
    __shared__ float t[32][33];
    const float* in; unsigned short* out;
    int R, C, Cpad, bx, by;
    if (id < 4096)      { in = W_in;  out = wt_in;  R = 1024; C = 4096; Cpad = 4096; bx = id & 127; by = id >> 7; }
    else if (id < 4352) { id -= 4096; in = W_x;  out = wt_x;  R = 2048; C = 96;  Cpad = 128;  bx = id & 3;  by = id >> 2; }
    else if (id < 4480) { id -= 4352; in = W_dt; out = wt_dt; R = 64;   C = 2048; Cpad = 2048; bx = id & 63; by = id >> 6; }
    else                { id -= 4480; in = W_out; out = wt_out; R = 2048; C = 1024; Cpad = 1024; bx = id & 31; by = id >> 5; }
    int c0 = bx * 32, r0 = by * 32;
    #pragma unroll
    for (int j = 0; j < 32; j += 8) {
        int r = r0 + ty + j, c = c0 + tx;
        t[ty + j][tx] = (r < R && c < C) ? in[(size_t)r * C + c] : 0.f;
    }
    __syncthreads();
    #pragma unroll
    for (int j = 0; j < 32; j += 8) {
        int c = c0 + ty + j, r = r0 + tx;
        if (c < Cpad && r < R) out[(size_t)c * R + r] = f2bf(t[tx][ty + j]);
    }
}

// ---------------- MFMA GEMM: C[M,N] = A[M,K](bf16) * Bt[N,K](bf16)^T ----------------
// EPI 2: bf16 store softplus(v+bias)                    (delta-proj)
// EPI 3: split-K fp32 partial, grid.x = 8 k-slices, single 128-wide N tile (x-proj)
// EPI 4: bf16 store                                     (in-proj)
// EPI 5: split-K bf16 partial, grid.z = 4 k-slices      (out-proj)
template<int EPI>
__global__ void gemm_mfma(const unsigned short* __restrict__ A,
                          const unsigned short* __restrict__ Bt,
                          float* __restrict__ C,
                          const float* __restrict__ ex1,
                          unsigned short* __restrict__ exb,
                          int M, int N, int K, int ldc) {
    __shared__ __attribute__((aligned(16))) unsigned short lds_a[128 * 32];
    __shared__ __attribute__((aligned(16))) unsigned short lds_b[128 * 32];
    const int tid = threadIdx.x;
    const int w = tid >> 6, lane = tid & 63;
    const int m0 = blockIdx.y * 128;
    const int n0 = (EPI == 3) ? 0 : blockIdx.x * 128;
    const int kstart = (EPI == 3) ? blockIdx.x * (K >> 3)
                     : (EPI == 5) ? blockIdx.z * (K >> 2) : 0;
    const int kend   = (EPI == 3) ? kstart + (K >> 3)
                     : (EPI == 5) ? kstart + (K >> 2) : K;
    const int wm = (w & 1) * 64, wn = (w >> 1) * 64;
    const int q = lane >> 4, r = lane & 15;
    const int srow = lane >> 2;          // 0..15
    const int scol = (lane & 3) * 8;     // 0,8,16,24

    f32x4 acc[4][4];
    f32x4 zero = {0.f, 0.f, 0.f, 0.f};
    #pragma unroll
    for (int i = 0; i < 4; ++i)
        #pragma unroll
        for (int j = 0; j < 4; ++j) acc[i][j] = zero;

    for (int kb = kstart; kb < kend; kb += 32) {
        __syncthreads();
        #pragma unroll
        for (int j = 0; j < 2; ++j) {
            int rbase = w * 32 + j * 16;
            gload_lds16(A  + (size_t)(m0 + rbase + srow) * K + kb + scol, lds_a + rbase * 32);
            gload_lds16(Bt + (size_t)(n0 + rbase + srow) * K + kb + scol, lds_b + rbase * 32);
        }
        __syncthreads();
        bf16x8 af[4], bfr[4];
        #pragma unroll
        for (int mi = 0; mi < 4; ++mi)
            af[mi] = *(const bf16x8*)(lds_a + (wm + mi * 16 + r) * 32 + q * 8);
        #pragma unroll
        for (int ni = 0; ni < 4; ++ni)
            bfr[ni] = *(const bf16x8*)(lds_b + (wn + ni * 16 + r) * 32 + q * 8);
        #pragma unroll
        for (int mi = 0; mi < 4; ++mi)
            #pragma unroll
            for (int ni = 0; ni < 4; ++ni)
                acc[mi][ni] = __builtin_amdgcn_mfma_f32_16x16x32_bf16(af[mi], bfr[ni], acc[mi][ni], 0, 0, 0);
    }

    #pragma unroll
    for (int mi = 0; mi < 4; ++mi) {
        #pragma unroll
        for (int ni = 0; ni < 4; ++ni) {
            f32x4 v = acc[mi][ni];
            int gmb = m0 + wm + mi * 16 + q * 4;
            int gn  = n0 + wn + ni * 16 + r;
            #pragma unroll
            for (int t = 0; t < 4; ++t) {
                int gm = gmb + t;
                float val = v[t];
                if (EPI == 2) {
                    val += ex1[gn];
                    val = fmaxf(val, 0.f) + log1pf(__expf(-fabsf(val)));
                    exb[(size_t)gm * ldc + gn] = f2bf(val);
                } else if (EPI == 3) {
                    C[((size_t)blockIdx.x * M + gm) * 128 + gn] = val;
                } else if (EPI == 4) {
                    exb[(size_t)gm * ldc + gn] = f2bf(val);
                } else {   // EPI 5
                    exb[((size_t)blockIdx.z * M + gm) * ldc + gn] = f2bf(val);
                }
            }
        }
    }
}

// ---------------- split-K reduce for x-proj: sum 8 partials, split dtlr/bc ----------------
__global__ void xproj_reduce(const float* __restrict__ Pp,
                             unsigned short* __restrict__ dtlr, float* __restrict__ bc) {
    int id = blockIdx.x * 256 + threadIdx.x;   // 4096*128
    int n = id & 127, m = id >> 7;
    if (n >= DR + 2 * NS) return;
    float s = 0.f;
    #pragma unroll
    for (int ks = 0; ks < 8; ++ks)
        s += Pp[((size_t)ks * MM + m) * 128 + n];
    if (n < DR) dtlr[(size_t)m * DR + n] = f2bf(s);
    else bc[(size_t)m * 32 + (n - DR)] = s;
}

// ---------------- split-K reduce for out-proj: out = residual + sum of 4 bf16 partials ----------------
__global__ void outproj_reduce(const unsigned short* __restrict__ Pp,
                               const float* __restrict__ resid, float* __restrict__ out) {
    int id = blockIdx.x * 256 + threadIdx.x;   // over MM*DM/4
    int c4 = id & 255;
    int m  = id >> 8;
    float4 s = ((const float4*)(resid + (size_t)m * DM))[c4];
    #pragma unroll
    for (int z = 0; z < 4; ++z) {
        ushort4 p = *(const ushort4*)(Pp + ((size_t)z * MM + m) * DM + c4 * 4);
        s.x += bf2f(p.x); s.y += bf2f(p.y); s.z += bf2f(p.z); s.w += bf2f(p.w);
    }
    ((float4*)(out + (size_t)m * DM))[c4] = s;
}

// ---------------- causal depthwise conv(K=4) + SiLU, 8 elements/thread ----------------
__global__ void conv_silu8(const unsigned short* __restrict__ xzb, const float* __restrict__ cw,
                           unsigned short* __restrict__ xab) {
    size_t idx8 = ((size_t)blockIdx.x * 256 + threadIdx.x) * 8;   // m*2048 + e
    int e = (int)(idx8 & (EI - 1));
    size_t m = idx8 >> 11;
    int l = (int)(m & (LL - 1));
    u16x8 x0 = *(const u16x8*)(xzb + m * 4096 + e);
    u16x8 zer = {0,0,0,0,0,0,0,0};
    u16x8 x1 = (l >= 1) ? *(const u16x8*)(xzb + (m - 1) * 4096 + e) : zer;
    u16x8 x2 = (l >= 2) ? *(const u16x8*)(xzb + (m - 2) * 4096 + e) : zer;
    u16x8 x3 = (l >= 3) ? *(const u16x8*)(xzb + (m - 3) * 4096 + e) : zer;
    u16x8 o;
    #pragma unroll
    for (int j = 0; j < 8; ++j) {
        float4 wv = ((const float4*)cw)[e + j];
        float s = bf2f(x0[j]) * wv.w + bf2f(x1[j]) * wv.z
                + bf2f(x2[j]) * wv.y + bf2f(x3[j]) * wv.x;
        float a = s / (1.f + __expf(-s));
        o[j] = f2bf(a);
    }
    *(u16x8*)(xab + idx8) = o;
}

// ---------------- selective scan, 3-phase chunked (CHUNK=16, NCHUNK=64) ----------------
// 8 states/thread; lanes l and l^32 share e. P/H/h0 layout: [((b*NC+c)*2048+e)*16+n] (n contiguous)
// phase1: per-chunk local scan -> P,H (bf16); bc staged in LDS
__global__ void scan_phase1(const unsigned short* __restrict__ dbufb, const unsigned short* __restrict__ xu,
                            const float* __restrict__ bc, const float* __restrict__ A_log,
                            unsigned short* __restrict__ P, unsigned short* __restrict__ H) {
    __shared__ float lbc[CHUNK * 32];   // 2 KB: this chunk's B|C rows
    int tid = threadIdx.x;
    int c = blockIdx.y, b = blockIdx.z;
    int mbase = b * LL + c * CHUNK;
    ((float2*)lbc)[tid] = ((const float2*)(bc + (size_t)mbase * 32))[tid];
    __syncthreads();
    int wv = tid >> 6, lane = tid & 63;
    int half = lane >> 5, el = lane & 31;
    int e = blockIdx.x * 128 + wv * 32 + el;
    int n0 = half * 8;
    float4 a0 = *(const float4*)(A_log + (size_t)e * NS + n0);
    float4 a1 = *(const float4*)(A_log + (size_t)e * NS + n0 + 4);
    float A[8] = {-expf(a0.x), -expf(a0.y), -expf(a0.z), -expf(a0.w),
                  -expf(a1.x), -expf(a1.y), -expf(a1.z), -expf(a1.w)};
    float h[8], p[8];
    #pragma unroll
    for (int j = 0; j < 8; ++j) { h[j] = 0.f; p[j] = 1.f; }
    for (int t = 0; t < CHUNK; ++t) {
        size_t m = (size_t)(mbase + t);
        float d = bf2f(dbufb[m * 2048 + e]);
        float u = bf2f(xu[m * 2048 + e]);
        float du = d * u;
        float4 b0 = *(const float4*)(lbc + t * 32 + n0);
        float4 b1 = *(const float4*)(lbc + t * 32 + n0 + 4);
        float Bv[8] = {b0.x, b0.y, b0.z, b0.w, b1.x, b1.y, b1.z, b1.w};
        #pragma unroll
        for (int j = 0; j < 8; ++j) {
            float dA = __expf(d * A[j]);
            p[j] *= dA;
            h[j] = fmaf(dA, h[j], du * Bv[j]);
        }
    }
    size_t obase = (((size_t)(b * NCHUNK + c) * 2048) + e) * NS + n0;
    u16x8 po, ho;
    #pragma unroll
    for (int j = 0; j < 8; ++j) { po[j] = f2bf(p[j]); ho[j] = f2bf(h[j]); }
    *(u16x8*)(P + obase) = po;
    *(u16x8*)(H + obase) = ho;
}

// phase2: one thread per (b,n,e), compose 64 chunks -> h0 (bf16) + hlast (fp32)
__global__ void scan_phase2(const unsigned short* __restrict__ P, const unsigned short* __restrict__ H,
                            unsigned short* __restrict__ h0, float* __restrict__ hlast) {
    int id = blockIdx.x * 256 + threadIdx.x;
    int e = id & (EI - 1);
    int bn = id >> 11;
    int n = bn & (NS - 1), b = bn >> 4;
    float h = 0.f;
    for (int c = 0; c < NCHUNK; ++c) {
        size_t ix = (((size_t)(b * NCHUNK + c) * 2048) + e) * NS + n;
        h0[ix] = f2bf(h);
        h = fmaf(bf2f(P[ix]), h, bf2f(H[ix]));
    }
    hlast[(((size_t)b * EI + e) * NS) + n] = h;
}

// phase3: rescan with h0; bc in LDS; y summed across halves via shfl_xor(32)
__global__ void scan_phase3(const unsigned short* __restrict__ dbufb, const unsigned short* __restrict__ xu,
                            const unsigned short* __restrict__ xzb,
                            const float* __restrict__ bc, const float* __restrict__ A_log,
                            const float* __restrict__ Dp, const unsigned short* __restrict__ h0,
                            unsigned short* __restrict__ ybf) {
    __shared__ float lbc[CHUNK * 32];
    int tid = threadIdx.x;
    int c = blockIdx.y, b = blockIdx.z;
    int mbase = b * LL + c * CHUNK;
    ((float2*)lbc)[tid] = ((const float2*)(bc + (size_t)mbase * 32))[tid];
    __syncthreads();
    int wv = tid >> 6, lane = tid & 63;
    int half = lane >> 5, el = lane & 31;
    int e = blockIdx.x * 128 + wv * 32 + el;
    int n0 = half * 8;
    float4 a0 = *(const float4*)(A_log + (size_t)e * NS + n0);
    float4 a1 = *(const float4*)(A_log + (size_t)e * NS + n0 + 4);
    float A[8] = {-expf(a0.x), -expf(a0.y), -expf(a0.z), -expf(a0.w),
                  -expf(a1.x), -expf(a1.y), -expf(a1.z), -expf(a1.w)};
    size_t obase = (((size_t)(b * NCHUNK + c) * 2048) + e) * NS + n0;
    u16x8 h0v = *(const u16x8*)(h0 + obase);
    float h[8];
    #pragma unroll
    for (int j = 0; j < 8; ++j) h[j] = bf2f(h0v[j]);
    float D = Dp[e];
    for (int t = 0; t < CHUNK; ++t) {
        size_t m = (size_t)(mbase + t);
        float d = bf2f(dbufb[m * 2048 + e]);
        float u = bf2f(xu[m * 2048 + e]);
        float du = d * u;
        float4 b0 = *(const float4*)(lbc + t * 32 + n0);
        float4 b1 = *(const float4*)(lbc + t * 32 + n0 + 4);
        float4 c0 = *(const float4*)(lbc + t * 32 + 16 + n0);
        float4 c1 = *(const float4*)(lbc + t * 32 + 16 + n0 + 4);
        float Bv[8] = {b0.x, b0.y, b0.z, b0.w, b1.x, b1.y, b1.z, b1.w};
        float Cv[8] = {c0.x, c0.y, c0.z, c0.w, c1.x, c1.y, c1.z, c1.w};
        float y = 0.f;
        #pragma unroll
        for (int j = 0; j < 8; ++j) {
            float dA = __expf(d * A[j]);
            h[j] = fmaf(dA, h[j], du * Bv[j]);
            y = fmaf(h[j], Cv[j], y);
        }
        y += __shfl_xor(y, 32);
        if (half == 0) {
            float z = bf2f(xzb[m * 4096 + 2048 + e]);
            float sil = z / (1.f + __expf(-z));
            float yt = fmaf(u, D, y);
            ybf[m * 2048 + e] = f2bf(yt * sil);
        }
    }
}

extern "C" void kernel_launch(void* const* d_in, const int* in_sizes, int n_in,
                              void* d_out, int out_size, void* d_ws, size_t ws_size,
                              hipStream_t stream) {
    (void)in_sizes; (void)n_in; (void)out_size; (void)ws_size;
    const float* hidden = (const float*)d_in[0];
    const float* norm_w = (const float*)d_in[1];
    const float* W_in   = (const float*)d_in[2];
    const float* conv_w = (const float*)d_in[3];
    const float* W_x    = (const float*)d_in[4];
    const float* W_dt   = (const float*)d_in[5];
    const float* b_dt   = (const float*)d_in[6];
    const float* A_log  = (const float*)d_in[7];
    const float* D_par  = (const float*)d_in[8];
    const float* W_out  = (const float*)d_in[9];
    float* out = (float*)d_out;
    char* ws = (char*)d_ws;
    const size_t MB = 1ull << 20;

    unsigned short* xzb      = (unsigned short*)(ws + 0);            // 32 MB bf16 (x_in|z)
    unsigned short* xact_bf  = (unsigned short*)(ws + 32 * MB);      // 16 MB
    unsigned short* xnorm_bf = (unsigned short*)(ws + 48 * MB);      //  8 MB
    unsigned short* wt_in    = (unsigned short*)(ws + 56 * MB);      //  8 MB
    unsigned short* wt_out   = (unsigned short*)(ws + 64 * MB);      //  4 MB
    unsigned short* wt_x     = (unsigned short*)(ws + 68 * MB);      // 512 KB (padded 96->128 rows)
    unsigned short* wt_dt    = (unsigned short*)(ws + 68 * MB + 512 * 1024);  // 256 KB
    unsigned short* dtlr     = (unsigned short*)(ws + 69 * MB);      // 512 KB
    float*          bc       = (float*)(ws + 69 * MB + 512 * 1024);  // 512 KB
    unsigned short* dbufb    = (unsigned short*)(ws + 70 * MB);      // 16 MB bf16 delta
    unsigned short* ybf      = (unsigned short*)(ws + 86 * MB);      // 16 MB
    unsigned short* P        = (unsigned short*)(ws + 102 * MB);     // 16 MB bf16
    unsigned short* Hb       = (unsigned short*)(ws + 118 * MB);     // 16 MB bf16
    unsigned short* h0       = (unsigned short*)(ws + 134 * MB);     // 16 MB bf16  (150 MB total)
    float* Ppart = (float*)P;            // 16 MB x-proj split-K fp32 partials (dead before phase1)
    unsigned short* Pout = P;            // 32 MB out-proj bf16 partials (P/Hb dead after phase2)
    float* hlast = out + (size_t)MM * DM;

    // pre-pass: all weight transposes + rmsnorm in one launch
    pre_all<<<10624, dim3(32, 8), 0, stream>>>(W_in, W_x, W_dt, W_out, hidden, norm_w,
                                               wt_in, wt_x, wt_dt, wt_out, xnorm_bf);
    // xzb = bf16( rmsnorm(x) @ W_in )   (M=4096, N=4096, K=1024)
    gemm_mfma<4><<<dim3(32, 32), 256, 0, stream>>>(xnorm_bf, wt_in, nullptr, nullptr, xzb,
                                                   MM, 4096, 1024, 4096);
    // x_act = silu(dwconv(x_in))  (bf16)
    conv_silu8<<<(MM * EI) / (256 * 8), 256, 0, stream>>>(xzb, conv_w, xact_bf);
    // x_db partials = x_act @ W_x, split-K over 8 slices (M=4096, N=128pad, K=2048)
    gemm_mfma<3><<<dim3(8, 32), 256, 0, stream>>>(xact_bf, wt_x, Ppart, nullptr, nullptr,
                                                  MM, 128, 2048, 128);
    xproj_reduce<<<(MM * 128) / 256, 256, 0, stream>>>(Ppart, dtlr, bc);
    // delta = bf16( softplus(dtlr @ W_dt + b_dt) )   (M=4096, N=2048, K=64)
    gemm_mfma<2><<<dim3(16, 32), 256, 0, stream>>>(dtlr, wt_dt, nullptr, b_dt, dbufb,
                                                   MM, 2048, 64, 2048);
    // chunked selective scan, 3 phases (CHUNK=16, 8 states/thread, bc in LDS)
    scan_phase1<<<dim3(16, NCHUNK, BB), 256, 0, stream>>>(dbufb, xact_bf, bc, A_log, P, Hb);
    scan_phase2<<<(BB * NS * EI) / 256, 256, 0, stream>>>(P, Hb, h0, hlast);
    scan_phase3<<<dim3(16, NCHUNK, BB), 256, 0, stream>>>(dbufb, xact_bf, xzb, bc, A_log, D_par,
                                                          h0, ybf);
    // out-proj split-K=4: partials = y @ W_out slices  (M=4096, N=1024, K=2048)
    gemm_mfma<5><<<dim3(8, 32, 4), 256, 0, stream>>>(ybf, wt_out, nullptr, nullptr, Pout,
                                                     MM, 1024, 2048, 1024);
    // out = residual + sum partials
    outproj_reduce<<<(MM * DM / 4) / 256, 256, 0, stream>>>(Pout, hidden, out);
}

// Round 7
// 353.847 us; speedup vs baseline: 1.0177x; 1.0177x over previous
//
#include <hip/hip_runtime.h>
#include <cstdint>
#include <cstddef>

// Problem constants (B=4, L=1024)
#define DM 1024      // D_MODEL
#define EI 2048      // E_INNER
#define NS 16        // N_STATE
#define DR 64        // DT_RANK
#define BB 4
#define LL 1024
#define MM (BB*LL)   // 4096 token rows
#define NCHUNK 64
#define CHUNK 16

typedef __attribute__((ext_vector_type(8))) __bf16 bf16x8;
typedef __attribute__((ext_vector_type(4))) float f32x4;
typedef __attribute__((ext_vector_type(8))) unsigned short u16x8;

__device__ __forceinline__ unsigned short f2bf(float f) {
    union { float f; unsigned int u; } v; v.f = f;
    unsigned int r = v.u + 0x7FFFu + ((v.u >> 16) & 1u);   // RNE
    return (unsigned short)(r >> 16);
}
__device__ __forceinline__ float bf2f(unsigned short u) {
    union { unsigned int u; float f; } v; v.u = ((unsigned int)u) << 16;
    return v.f;
}

__device__ __forceinline__ void gload_lds16(const unsigned short* g, unsigned short* l) {
    __builtin_amdgcn_global_load_lds(
        (const __attribute__((address_space(1))) unsigned int*)g,
        (__attribute__((address_space(3))) unsigned int*)l, 16, 0, 0);
}

// ---------------- fused pre-pass: 4 weight transposes + RMSNorm, one launch ----------------
__global__ void pre_all(const float* __restrict__ W_in, const float* __restrict__ W_x,
                        const float* __restrict__ W_dt, const float* __restrict__ W_out,
                        const float* __restrict__ x, const float* __restrict__ nw,
                        unsigned short* __restrict__ wt_in, unsigned short* __restrict__ wt_x,
                        unsigned short* __restrict__ wt_dt, unsigned short* __restrict__ wt_out,
                        unsigned short* __restrict__ xnorm) {
    int id = blockIdx.x;
    int tx = threadIdx.x, ty = threadIdx.y;
    if (id >= 6528) {   // ---- rmsnorm ----
        int m = id - 6528, tid = ty * 32 + tx;
        const float4* row = (const float4*)(x + (size_t)m * DM);
        float4 v = row[tid];
        float ss = v.x*v.x + v.y*v.y + v.z*v.z + v.w*v.w;
        #pragma unroll
        for (int o = 32; o; o >>= 1) ss += __shfl_down(ss, o);
        __shared__ float red[4];
        if ((tid & 63) == 0) red[tid >> 6] = ss;
        __syncthreads();
        ss = red[0] + red[1] + red[2] + red[3];
        float scale = rsqrtf(ss * (1.0f / DM) + 1e-6f);
        float4 wv = ((const float4*)nw)[tid];
        ushort4 o4;
        o4.x = f2bf(v.x * scale * wv.x);
        o4.y = f2bf(v.y * scale * wv.y);
        o4.z = f2bf(v.z * scale * wv.z);
        o4.w = f2bf(v.w * scale * wv.w);
        ((ushort4*)xnorm)[(size_t)m * (DM/4) + tid] = o4;
        return;
    }
    // ---- transpose fp32 (R,C) -> bf16 (Cpad,R) ----
    __shared__ float t[32][33];
    const float* in; unsigned short* out;
    int R, C, Cpad, bx, by;
    if (id < 4096)      { in = W_in;  out = wt_in;  R = 1024; C = 4096; Cpad = 4096; bx = id & 127; by = id >> 7; }
    else if (id < 4352) { id -= 4096; in = W_x;  out = wt_x;  R = 2048; C = 96;  Cpad = 128;  bx = id & 3;  by = id >> 2; }
    else if (id < 4480) { id -= 4352; in = W_dt; out = wt_dt; R = 64;   C = 2048; Cpad = 2048; bx = id & 63; by = id >> 6; }
    else                { id -= 4480; in = W_out; out = wt_out; R = 2048; C = 1024; Cpad = 1024; bx = id & 31; by = id >> 5; }
    int c0 = bx * 32, r0 = by * 32;
    #pragma unroll
    for (int j = 0; j < 32; j += 8) {
        int r = r0 + ty + j, c = c0 + tx;
        t[ty + j][tx] = (r < R && c < C) ? in[(size_t)r * C + c] : 0.f;
    }
    __syncthreads();
    #pragma unroll
    for (int j = 0; j < 32; j += 8) {
        int c = c0 + ty + j, r = r0 + tx;
        if (c < Cpad && r < R) out[(size_t)c * R + r] = f2bf(t[tx][ty + j]);
    }
}

// ---------------- MFMA GEMM: C[M,N] = A[M,K](bf16) * Bt[N,K](bf16)^T ----------------
// EPI 2: bf16 store softplus(v+bias)                    (delta-proj)
// EPI 3: split-K fp32 partial, grid.x = 8 k-slices, single 128-wide N tile (x-proj)
// EPI 4: bf16 store                                     (in-proj)
// EPI 5: split-K bf16 partial, grid.z = 4 k-slices      (out-proj)
template<int EPI>
__global__ void gemm_mfma(const unsigned short* __restrict__ A,
                          const unsigned short* __restrict__ Bt,
                          float* __restrict__ C,
                          const float* __restrict__ ex1,
                          unsigned short* __restrict__ exb,
                          int M, int N, int K, int ldc) {
    __shared__ __attribute__((aligned(16))) unsigned short lds_a[128 * 32];
    __shared__ __attribute__((aligned(16))) unsigned short lds_b[128 * 32];
    const int tid = threadIdx.x;
    const int w = tid >> 6, lane = tid & 63;
    const int m0 = blockIdx.y * 128;
    const int n0 = (EPI == 3) ? 0 : blockIdx.x * 128;
    const int kstart = (EPI == 3) ? blockIdx.x * (K >> 3)
                     : (EPI == 5) ? blockIdx.z * (K >> 2) : 0;
    const int kend   = (EPI == 3) ? kstart + (K >> 3)
                     : (EPI == 5) ? kstart + (K >> 2) : K;
    const int wm = (w & 1) * 64, wn = (w >> 1) * 64;
    const int q = lane >> 4, r = lane & 15;
    const int srow = lane >> 2;          // 0..15
    const int scol = (lane & 3) * 8;     // 0,8,16,24

    f32x4 acc[4][4];
    f32x4 zero = {0.f, 0.f, 0.f, 0.f};
    #pragma unroll
    for (int i = 0; i < 4; ++i)
        #pragma unroll
        for (int j = 0; j < 4; ++j) acc[i][j] = zero;

    for (int kb = kstart; kb < kend; kb += 32) {
        __syncthreads();
        #pragma unroll
        for (int j = 0; j < 2; ++j) {
            int rbase = w * 32 + j * 16;
            gload_lds16(A  + (size_t)(m0 + rbase + srow) * K + kb + scol, lds_a + rbase * 32);
            gload_lds16(Bt + (size_t)(n0 + rbase + srow) * K + kb + scol, lds_b + rbase * 32);
        }
        __syncthreads();
        bf16x8 af[4], bfr[4];
        #pragma unroll
        for (int mi = 0; mi < 4; ++mi)
            af[mi] = *(const bf16x8*)(lds_a + (wm + mi * 16 + r) * 32 + q * 8);
        #pragma unroll
        for (int ni = 0; ni < 4; ++ni)
            bfr[ni] = *(const bf16x8*)(lds_b + (wn + ni * 16 + r) * 32 + q * 8);
        #pragma unroll
        for (int mi = 0; mi < 4; ++mi)
            #pragma unroll
            for (int ni = 0; ni < 4; ++ni)
                acc[mi][ni] = __builtin_amdgcn_mfma_f32_16x16x32_bf16(af[mi], bfr[ni], acc[mi][ni], 0, 0, 0);
    }

    #pragma unroll
    for (int mi = 0; mi < 4; ++mi) {
        #pragma unroll
        for (int ni = 0; ni < 4; ++ni) {
            f32x4 v = acc[mi][ni];
            int gmb = m0 + wm + mi * 16 + q * 4;
            int gn  = n0 + wn + ni * 16 + r;
            #pragma unroll
            for (int t = 0; t < 4; ++t) {
                int gm = gmb + t;
                float val = v[t];
                if (EPI == 2) {
                    val += ex1[gn];
                    val = fmaxf(val, 0.f) + log1pf(__expf(-fabsf(val)));
                    exb[(size_t)gm * ldc + gn] = f2bf(val);
                } else if (EPI == 3) {
                    C[((size_t)blockIdx.x * M + gm) * 128 + gn] = val;
                } else if (EPI == 4) {
                    exb[(size_t)gm * ldc + gn] = f2bf(val);
                } else {   // EPI 5
                    exb[((size_t)blockIdx.z * M + gm) * ldc + gn] = f2bf(val);
                }
            }
        }
    }
}

// ---------------- split-K reduce for x-proj: sum 8 partials, split dtlr/bc ----------------
__global__ void xproj_reduce(const float* __restrict__ Pp,
                             unsigned short* __restrict__ dtlr, float* __restrict__ bc) {
    int id = blockIdx.x * 256 + threadIdx.x;   // 4096*128
    int n = id & 127, m = id >> 7;
    if (n >= DR + 2 * NS) return;
    float s = 0.f;
    #pragma unroll
    for (int ks = 0; ks < 8; ++ks)
        s += Pp[((size_t)ks * MM + m) * 128 + n];
    if (n < DR) dtlr[(size_t)m * DR + n] = f2bf(s);
    else bc[(size_t)m * 32 + (n - DR)] = s;
}

// ---------------- split-K reduce for out-proj: out = residual + sum of 4 bf16 partials ----------------
__global__ void outproj_reduce(const unsigned short* __restrict__ Pp,
                               const float* __restrict__ resid, float* __restrict__ out) {
    int id = blockIdx.x * 256 + threadIdx.x;   // over MM*DM/4
    int c4 = id & 255;
    int m  = id >> 8;
    float4 s = ((const float4*)(resid + (size_t)m * DM))[c4];
    #pragma unroll
    for (int z = 0; z < 4; ++z) {
        ushort4 p = *(const ushort4*)(Pp + ((size_t)z * MM + m) * DM + c4 * 4);
        s.x += bf2f(p.x); s.y += bf2f(p.y); s.z += bf2f(p.z); s.w += bf2f(p.w);
    }
    ((float4*)(out + (size_t)m * DM))[c4] = s;
}

// ---------------- causal depthwise conv(K=4) + SiLU, 8 elements/thread ----------------
__global__ void conv_silu8(const unsigned short* __restrict__ xzb, const float* __restrict__ cw,
                           unsigned short* __restrict__ xab) {
    size_t idx8 = ((size_t)blockIdx.x * 256 + threadIdx.x) * 8;   // m*2048 + e
    int e = (int)(idx8 & (EI - 1));
    size_t m = idx8 >> 11;
    int l = (int)(m & (LL - 1));
    u16x8 x0 = *(const u16x8*)(xzb + m * 4096 + e);
    u16x8 zer = {0,0,0,0,0,0,0,0};
    u16x8 x1 = (l >= 1) ? *(const u16x8*)(xzb + (m - 1) * 4096 + e) : zer;
    u16x8 x2 = (l >= 2) ? *(const u16x8*)(xzb + (m - 2) * 4096 + e) : zer;
    u16x8 x3 = (l >= 3) ? *(const u16x8*)(xzb + (m - 3) * 4096 + e) : zer;
    u16x8 o;
    #pragma unroll
    for (int j = 0; j < 8; ++j) {
        float4 wv = ((const float4*)cw)[e + j];
        float s = bf2f(x0[j]) * wv.w + bf2f(x1[j]) * wv.z
                + bf2f(x2[j]) * wv.y + bf2f(x3[j]) * wv.x;
        float a = s / (1.f + __expf(-s));
        o[j] = f2bf(a);
    }
    *(u16x8*)(xab + idx8) = o;
}

// ---------------- selective scan, 3-phase chunked (CHUNK=16, NCHUNK=64) ----------------
// ONE thread per e: all 16 states in registers; B/C read at uniform addresses
// (scalar-pipe loads); no LDS, no shfl. P/H/h0 layout: [((b*NC+c)*2048+e)*16+n].
__global__ void scan_phase1(const unsigned short* __restrict__ dbufb, const unsigned short* __restrict__ xu,
                            const float* __restrict__ bc, const float* __restrict__ A_log,
                            unsigned short* __restrict__ P, unsigned short* __restrict__ H) {
    int tid = threadIdx.x;
    int c = blockIdx.y, b = blockIdx.z;
    int e = blockIdx.x * 256 + tid;
    int mbase = b * LL + c * CHUNK;
    float A[NS], h[NS], p[NS];
    #pragma unroll
    for (int j = 0; j < NS; j += 4) {
        float4 a = *(const float4*)(A_log + (size_t)e * NS + j);
        A[j] = -expf(a.x); A[j+1] = -expf(a.y); A[j+2] = -expf(a.z); A[j+3] = -expf(a.w);
    }
    #pragma unroll
    for (int j = 0; j < NS; ++j) { h[j] = 0.f; p[j] = 1.f; }
    const unsigned short* dp = dbufb + (size_t)mbase * 2048 + e;
    const unsigned short* up = xu    + (size_t)mbase * 2048 + e;
    for (int t = 0; t < CHUNK; ++t) {
        float d = bf2f(dp[(size_t)t * 2048]);
        float u = bf2f(up[(size_t)t * 2048]);
        float du = d * u;
        const float4* bv = (const float4*)(bc + (size_t)(mbase + t) * 32);  // uniform addr
        #pragma unroll
        for (int q4 = 0; q4 < 4; ++q4) {
            float4 Bq = bv[q4];
            float Bj[4] = {Bq.x, Bq.y, Bq.z, Bq.w};
            #pragma unroll
            for (int k = 0; k < 4; ++k) {
                int j = q4 * 4 + k;
                float dA = __expf(d * A[j]);
                p[j] *= dA;
                h[j] = fmaf(dA, h[j], du * Bj[k]);
            }
        }
    }
    size_t obase = (((size_t)(b * NCHUNK + c) * 2048) + e) * NS;
    u16x8 o0, o1;
    #pragma unroll
    for (int j = 0; j < 8; ++j) { o0[j] = f2bf(p[j]); o1[j] = f2bf(p[j + 8]); }
    *(u16x8*)(P + obase) = o0;
    *(u16x8*)(P + obase + 8) = o1;
    #pragma unroll
    for (int j = 0; j < 8; ++j) { o0[j] = f2bf(h[j]); o1[j] = f2bf(h[j + 8]); }
    *(u16x8*)(H + obase) = o0;
    *(u16x8*)(H + obase + 8) = o1;
}

// phase2: one thread per (b,n,e), compose 64 chunks -> h0 (bf16) + hlast (fp32)
__global__ void scan_phase2(const unsigned short* __restrict__ P, const unsigned short* __restrict__ H,
                            unsigned short* __restrict__ h0, float* __restrict__ hlast) {
    int id = blockIdx.x * 256 + threadIdx.x;
    int e = id & (EI - 1);
    int bn = id >> 11;
    int n = bn & (NS - 1), b = bn >> 4;
    float h = 0.f;
    for (int c = 0; c < NCHUNK; ++c) {
        size_t ix = (((size_t)(b * NCHUNK + c) * 2048) + e) * NS + n;
        h0[ix] = f2bf(h);
        h = fmaf(bf2f(P[ix]), h, bf2f(H[ix]));
    }
    hlast[(((size_t)b * EI + e) * NS) + n] = h;
}

// phase3: rescan with h0; B/C uniform-address loads; full y in-thread
__global__ void scan_phase3(const unsigned short* __restrict__ dbufb, const unsigned short* __restrict__ xu,
                            const unsigned short* __restrict__ xzb,
                            const float* __restrict__ bc, const float* __restrict__ A_log,
                            const float* __restrict__ Dp, const unsigned short* __restrict__ h0,
                            unsigned short* __restrict__ ybf) {
    int tid = threadIdx.x;
    int c = blockIdx.y, b = blockIdx.z;
    int e = blockIdx.x * 256 + tid;
    int mbase = b * LL + c * CHUNK;
    float A[NS], h[NS];
    #pragma unroll
    for (int j = 0; j < NS; j += 4) {
        float4 a = *(const float4*)(A_log + (size_t)e * NS + j);
        A[j] = -expf(a.x); A[j+1] = -expf(a.y); A[j+2] = -expf(a.z); A[j+3] = -expf(a.w);
    }
    size_t obase = (((size_t)(b * NCHUNK + c) * 2048) + e) * NS;
    u16x8 h0a = *(const u16x8*)(h0 + obase);
    u16x8 h0b = *(const u16x8*)(h0 + obase + 8);
    #pragma unroll
    for (int j = 0; j < 8; ++j) { h[j] = bf2f(h0a[j]); h[j + 8] = bf2f(h0b[j]); }
    float D = Dp[e];
    const unsigned short* dp = dbufb + (size_t)mbase * 2048 + e;
    const unsigned short* up = xu    + (size_t)mbase * 2048 + e;
    const unsigned short* zp = xzb   + (size_t)mbase * 4096 + 2048 + e;
    unsigned short* yp = ybf + (size_t)mbase * 2048 + e;
    for (int t = 0; t < CHUNK; ++t) {
        float d = bf2f(dp[(size_t)t * 2048]);
        float u = bf2f(up[(size_t)t * 2048]);
        float du = d * u;
        const float4* bv = (const float4*)(bc + (size_t)(mbase + t) * 32);  // uniform addr
        float y = 0.f;
        #pragma unroll
        for (int q4 = 0; q4 < 2; ++q4) {
            float4 Bq0 = bv[q4 * 2], Bq1 = bv[q4 * 2 + 1];
            float4 Cq0 = bv[4 + q4 * 2], Cq1 = bv[4 + q4 * 2 + 1];
            float Bj[8] = {Bq0.x, Bq0.y, Bq0.z, Bq0.w, Bq1.x, Bq1.y, Bq1.z, Bq1.w};
            float Cj[8] = {Cq0.x, Cq0.y, Cq0.z, Cq0.w, Cq1.x, Cq1.y, Cq1.z, Cq1.w};
            #pragma unroll
            for (int k = 0; k < 8; ++k) {
                int j = q4 * 8 + k;
                float dA = __expf(d * A[j]);
                h[j] = fmaf(dA, h[j], du * Bj[k]);
                y = fmaf(h[j], Cj[k], y);
            }
        }
        float z = bf2f(zp[(size_t)t * 4096]);
        float sil = z / (1.f + __expf(-z));
        float yt = fmaf(u, D, y);
        yp[(size_t)t * 2048] = f2bf(yt * sil);
    }
}

extern "C" void kernel_launch(void* const* d_in, const int* in_sizes, int n_in,
                              void* d_out, int out_size, void* d_ws, size_t ws_size,
                              hipStream_t stream) {
    (void)in_sizes; (void)n_in; (void)out_size; (void)ws_size;
    const float* hidden = (const float*)d_in[0];
    const float* norm_w = (const float*)d_in[1];
    const float* W_in   = (const float*)d_in[2];
    const float* conv_w = (const float*)d_in[3];
    const float* W_x    = (const float*)d_in[4];
    const float* W_dt   = (const float*)d_in[5];
    const float* b_dt   = (const float*)d_in[6];
    const float* A_log  = (const float*)d_in[7];
    const float* D_par  = (const float*)d_in[8];
    const float* W_out  = (const float*)d_in[9];
    float* out = (float*)d_out;
    char* ws = (char*)d_ws;
    const size_t MB = 1ull << 20;

    unsigned short* xzb      = (unsigned short*)(ws + 0);            // 32 MB bf16 (x_in|z)
    unsigned short* xact_bf  = (unsigned short*)(ws + 32 * MB);      // 16 MB
    unsigned short* xnorm_bf = (unsigned short*)(ws + 48 * MB);      //  8 MB
    unsigned short* wt_in    = (unsigned short*)(ws + 56 * MB);      //  8 MB
    unsigned short* wt_out   = (unsigned short*)(ws + 64 * MB);      //  4 MB
    unsigned short* wt_x     = (unsigned short*)(ws + 68 * MB);      // 512 KB (padded 96->128 rows)
    unsigned short* wt_dt    = (unsigned short*)(ws + 68 * MB + 512 * 1024);  // 256 KB
    unsigned short* dtlr     = (unsigned short*)(ws + 69 * MB);      // 512 KB
    float*          bc       = (float*)(ws + 69 * MB + 512 * 1024);  // 512 KB
    unsigned short* dbufb    = (unsigned short*)(ws + 70 * MB);      // 16 MB bf16 delta
    unsigned short* ybf      = (unsigned short*)(ws + 86 * MB);      // 16 MB
    unsigned short* P        = (unsigned short*)(ws + 102 * MB);     // 16 MB bf16
    unsigned short* Hb       = (unsigned short*)(ws + 118 * MB);     // 16 MB bf16
    unsigned short* h0       = (unsigned short*)(ws + 134 * MB);     // 16 MB bf16  (150 MB total)
    float* Ppart = (float*)P;            // 16 MB x-proj split-K fp32 partials (dead before phase1)
    unsigned short* Pout = P;            // 32 MB out-proj bf16 partials (P/Hb dead after phase2)
    float* hlast = out + (size_t)MM * DM;

    // pre-pass: all weight transposes + rmsnorm in one launch
    pre_all<<<10624, dim3(32, 8), 0, stream>>>(W_in, W_x, W_dt, W_out, hidden, norm_w,
                                               wt_in, wt_x, wt_dt, wt_out, xnorm_bf);
    // xzb = bf16( rmsnorm(x) @ W_in )   (M=4096, N=4096, K=1024)
    gemm_mfma<4><<<dim3(32, 32), 256, 0, stream>>>(xnorm_bf, wt_in, nullptr, nullptr, xzb,
                                                   MM, 4096, 1024, 4096);
    // x_act = silu(dwconv(x_in))  (bf16)
    conv_silu8<<<(MM * EI) / (256 * 8), 256, 0, stream>>>(xzb, conv_w, xact_bf);
    // x_db partials = x_act @ W_x, split-K over 8 slices (M=4096, N=128pad, K=2048)
    gemm_mfma<3><<<dim3(8, 32), 256, 0, stream>>>(xact_bf, wt_x, Ppart, nullptr, nullptr,
                                                  MM, 128, 2048, 128);
    xproj_reduce<<<(MM * 128) / 256, 256, 0, stream>>>(Ppart, dtlr, bc);
    // delta = bf16( softplus(dtlr @ W_dt + b_dt) )   (M=4096, N=2048, K=64)
    gemm_mfma<2><<<dim3(16, 32), 256, 0, stream>>>(dtlr, wt_dt, nullptr, b_dt, dbufb,
                                                   MM, 2048, 64, 2048);
    // chunked selective scan, 3 phases (CHUNK=16, 16 states/thread, scalar B/C)
    scan_phase1<<<dim3(8, NCHUNK, BB), 256, 0, stream>>>(dbufb, xact_bf, bc, A_log, P, Hb);
    scan_phase2<<<(BB * NS * EI) / 256, 256, 0, stream>>>(P, Hb, h0, hlast);
    scan_phase3<<<dim3(8, NCHUNK, BB), 256, 0, stream>>>(dbufb, xact_bf, xzb, bc, A_log, D_par,
                                                         h0, ybf);
    // out-proj split-K=4: partials = y @ W_out slices  (M=4096, N=1024, K=2048)
    gemm_mfma<5><<<dim3(8, 32, 4), 256, 0, stream>>>(ybf, wt_out, nullptr, nullptr, Pout,
                                                     MM, 1024, 2048, 1024);
    // out = residual + sum partials
    outproj_reduce<<<(MM * DM / 4) / 256, 256, 0, stream>>>(Pout, hidden, out);
}

// Round 8
// 334.316 us; speedup vs baseline: 1.0772x; 1.0584x over previous
//
#include <hip/hip_runtime.h>
#include <cstdint>
#include <cstddef>

// Problem constants (B=4, L=1024)
#define DM 1024      // D_MODEL
#define EI 2048      // E_INNER
#define NS 16        // N_STATE
#define DR 64        // DT_RANK
#define BB 4
#define LL 1024
#define MM (BB*LL)   // 4096 token rows
#define NCHUNK 32
#define CHUNK 32

typedef __attribute__((ext_vector_type(8))) __bf16 bf16x8;
typedef __attribute__((ext_vector_type(4))) float f32x4;
typedef __attribute__((ext_vector_type(8))) unsigned short u16x8;

__device__ __forceinline__ unsigned short f2bf(float f) {
    union { float f; unsigned int u; } v; v.f = f;
    unsigned int r = v.u + 0x7FFFu + ((v.u >> 16) & 1u);   // RNE
    return (unsigned short)(r >> 16);
}
__device__ __forceinline__ float bf2f(unsigned short u) {
    union { unsigned int u; float f; } v; v.u = ((unsigned int)u) << 16;
    return v.f;
}

__device__ __forceinline__ void gload_lds16(const unsigned short* g, unsigned short* l) {
    __builtin_amdgcn_global_load_lds(
        (const __attribute__((address_space(1))) unsigned int*)g,
        (__attribute__((address_space(3))) unsigned int*)l, 16, 0, 0);
}

// ---------------- fused pre-pass: 4 weight transposes + RMSNorm, one launch ----------------
__global__ void pre_all(const float* __restrict__ W_in, const float* __restrict__ W_x,
                        const float* __restrict__ W_dt, const float* __restrict__ W_out,
                        const float* __restrict__ x, const float* __restrict__ nw,
                        unsigned short* __restrict__ wt_in, unsigned short* __restrict__ wt_x,
                        unsigned short* __restrict__ wt_dt, unsigned short* __restrict__ wt_out,
                        unsigned short* __restrict__ xnorm) {
    int id = blockIdx.x;
    int tx = threadIdx.x, ty = threadIdx.y;
    if (id >= 6528) {   // ---- rmsnorm ----
        int m = id - 6528, tid = ty * 32 + tx;
        const float4* row = (const float4*)(x + (size_t)m * DM);
        float4 v = row[tid];
        float ss = v.x*v.x + v.y*v.y + v.z*v.z + v.w*v.w;
        #pragma unroll
        for (int o = 32; o; o >>= 1) ss += __shfl_down(ss, o);
        __shared__ float red[4];
        if ((tid & 63) == 0) red[tid >> 6] = ss;
        __syncthreads();
        ss = red[0] + red[1] + red[2] + red[3];
        float scale = rsqrtf(ss * (1.0f / DM) + 1e-6f);
        float4 wv = ((const float4*)nw)[tid];
        ushort4 o4;
        o4.x = f2bf(v.x * scale * wv.x);
        o4.y = f2bf(v.y * scale * wv.y);
        o4.z = f2bf(v.z * scale * wv.z);
        o4.w = f2bf(v.w * scale * wv.w);
        ((ushort4*)xnorm)[(size_t)m * (DM/4) + tid] = o4;
        return;
    }
    // ---- transpose fp32 (R,C) -> bf16 (Cpad,R) ----
    __shared__ float t[32][33];
    const float* in; unsigned short* out;
    int R, C, Cpad, bx, by;
    if (id < 4096)      { in = W_in;  out = wt_in;  R = 1024; C = 4096; Cpad = 4096; bx = id & 127; by = id >> 7; }
    else if (id < 4352) { id -= 4096; in = W_x;  out = wt_x;  R = 2048; C = 96;  Cpad = 128;  bx = id & 3;  by = id >> 2; }
    else if (id < 4480) { id -= 4352; in = W_dt; out = wt_dt; R = 64;   C = 2048; Cpad = 2048; bx = id & 63; by = id >> 6; }
    else                { id -= 4480; in = W_out; out = wt_out; R = 2048; C = 1024; Cpad = 1024; bx = id & 31; by = id >> 5; }
    int c0 = bx * 32, r0 = by * 32;
    #pragma unroll
    for (int j = 0; j < 32; j += 8) {
        int r = r0 + ty + j, c = c0 + tx;
        t[ty + j][tx] = (r < R && c < C) ? in[(size_t)r * C + c] : 0.f;
    }
    __syncthreads();
    #pragma unroll
    for (int j = 0; j < 32; j += 8) {
        int c = c0 + ty + j, r = r0 + tx;
        if (c < Cpad && r < R) out[(size_t)c * R + r] = f2bf(t[tx][ty + j]);
    }
}

// ---------------- MFMA GEMM body: C[M,N] = A[M,K](bf16) * Bt[N,K](bf16)^T ----------------
// EPI 2: bf16 store softplus(v+bias)                    (delta-proj)
// EPI 3: split-K fp32 partial, grid.x = 8 k-slices, single 128-wide N tile (x-proj)
// EPI 4: bf16 store                                     (in-proj)
// EPI 5: split-K bf16 partial, grid.z = 4 k-slices      (out-proj)
template<int EPI>
__device__ __forceinline__ void gemm_body(const unsigned short* __restrict__ A,
                                          const unsigned short* __restrict__ Bt,
                                          float* __restrict__ C,
                                          const float* __restrict__ ex1,
                                          unsigned short* __restrict__ exb,
                                          int M, int N, int K, int ldc) {
    __shared__ __attribute__((aligned(16))) unsigned short lds_a[128 * 32];
    __shared__ __attribute__((aligned(16))) unsigned short lds_b[128 * 32];
    const int tid = threadIdx.x;
    const int w = tid >> 6, lane = tid & 63;
    const int m0 = blockIdx.y * 128;
    const int n0 = (EPI == 3) ? 0 : blockIdx.x * 128;
    const int kstart = (EPI == 3) ? blockIdx.x * (K >> 3)
                     : (EPI == 5) ? blockIdx.z * (K >> 2) : 0;
    const int kend   = (EPI == 3) ? kstart + (K >> 3)
                     : (EPI == 5) ? kstart + (K >> 2) : K;
    const int wm = (w & 1) * 64, wn = (w >> 1) * 64;
    const int q = lane >> 4, r = lane & 15;
    const int srow = lane >> 2;          // 0..15
    const int scol = (lane & 3) * 8;     // 0,8,16,24

    f32x4 acc[4][4];
    f32x4 zero = {0.f, 0.f, 0.f, 0.f};
    #pragma unroll
    for (int i = 0; i < 4; ++i)
        #pragma unroll
        for (int j = 0; j < 4; ++j) acc[i][j] = zero;

    for (int kb = kstart; kb < kend; kb += 32) {
        __syncthreads();
        #pragma unroll
        for (int j = 0; j < 2; ++j) {
            int rbase = w * 32 + j * 16;
            gload_lds16(A  + (size_t)(m0 + rbase + srow) * K + kb + scol, lds_a + rbase * 32);
            gload_lds16(Bt + (size_t)(n0 + rbase + srow) * K + kb + scol, lds_b + rbase * 32);
        }
        __syncthreads();
        bf16x8 af[4], bfr[4];
        #pragma unroll
        for (int mi = 0; mi < 4; ++mi)
            af[mi] = *(const bf16x8*)(lds_a + (wm + mi * 16 + r) * 32 + q * 8);
        #pragma unroll
        for (int ni = 0; ni < 4; ++ni)
            bfr[ni] = *(const bf16x8*)(lds_b + (wn + ni * 16 + r) * 32 + q * 8);
        #pragma unroll
        for (int mi = 0; mi < 4; ++mi)
            #pragma unroll
            for (int ni = 0; ni < 4; ++ni)
                acc[mi][ni] = __builtin_amdgcn_mfma_f32_16x16x32_bf16(af[mi], bfr[ni], acc[mi][ni], 0, 0, 0);
    }

    #pragma unroll
    for (int mi = 0; mi < 4; ++mi) {
        #pragma unroll
        for (int ni = 0; ni < 4; ++ni) {
            f32x4 v = acc[mi][ni];
            int gmb = m0 + wm + mi * 16 + q * 4;
            int gn  = n0 + wn + ni * 16 + r;
            #pragma unroll
            for (int t = 0; t < 4; ++t) {
                int gm = gmb + t;
                float val = v[t];
                if (EPI == 2) {
                    val += ex1[gn];
                    val = fmaxf(val, 0.f) + log1pf(__expf(-fabsf(val)));
                    exb[(size_t)gm * ldc + gn] = f2bf(val);
                } else if (EPI == 3) {
                    C[((size_t)blockIdx.x * M + gm) * 128 + gn] = val;
                } else if (EPI == 4) {
                    exb[(size_t)gm * ldc + gn] = f2bf(val);
                } else {   // EPI 5
                    exb[((size_t)blockIdx.z * M + gm) * ldc + gn] = f2bf(val);
                }
            }
        }
    }
}

// distinct kernel symbols so rocprof rows are attributable
__global__ void g_inproj(const unsigned short* __restrict__ A, const unsigned short* __restrict__ Bt,
                         unsigned short* __restrict__ exb, int M, int N, int K, int ldc) {
    gemm_body<4>(A, Bt, nullptr, nullptr, exb, M, N, K, ldc);
}
__global__ void g_xproj(const unsigned short* __restrict__ A, const unsigned short* __restrict__ Bt,
                        float* __restrict__ C, int M, int N, int K, int ldc) {
    gemm_body<3>(A, Bt, C, nullptr, nullptr, M, N, K, ldc);
}
__global__ void g_dtproj(const unsigned short* __restrict__ A, const unsigned short* __restrict__ Bt,
                         const float* __restrict__ ex1, unsigned short* __restrict__ exb,
                         int M, int N, int K, int ldc) {
    gemm_body<2>(A, Bt, nullptr, ex1, exb, M, N, K, ldc);
}
__global__ void g_outproj(const unsigned short* __restrict__ A, const unsigned short* __restrict__ Bt,
                          unsigned short* __restrict__ exb, int M, int N, int K, int ldc) {
    gemm_body<5>(A, Bt, nullptr, nullptr, exb, M, N, K, ldc);
}

// ---------------- split-K reduce for x-proj: sum 8 partials, split dtlr/bc ----------------
__global__ void xproj_reduce(const float* __restrict__ Pp,
                             unsigned short* __restrict__ dtlr, float* __restrict__ bc) {
    int id = blockIdx.x * 256 + threadIdx.x;   // 4096*128
    int n = id & 127, m = id >> 7;
    if (n >= DR + 2 * NS) return;
    float s = 0.f;
    #pragma unroll
    for (int ks = 0; ks < 8; ++ks)
        s += Pp[((size_t)ks * MM + m) * 128 + n];
    if (n < DR) dtlr[(size_t)m * DR + n] = f2bf(s);
    else bc[(size_t)m * 32 + (n - DR)] = s;
}

// ---------------- split-K reduce for out-proj: out = residual + sum of 4 bf16 partials ----------------
__global__ void outproj_reduce(const unsigned short* __restrict__ Pp,
                               const float* __restrict__ resid, float* __restrict__ out) {
    int id = blockIdx.x * 256 + threadIdx.x;   // over MM*DM/4
    int c4 = id & 255;
    int m  = id >> 8;
    float4 s = ((const float4*)(resid + (size_t)m * DM))[c4];
    #pragma unroll
    for (int z = 0; z < 4; ++z) {
        ushort4 p = *(const ushort4*)(Pp + ((size_t)z * MM + m) * DM + c4 * 4);
        s.x += bf2f(p.x); s.y += bf2f(p.y); s.z += bf2f(p.z); s.w += bf2f(p.w);
    }
    ((float4*)(out + (size_t)m * DM))[c4] = s;
}

// ---------------- causal depthwise conv(K=4) + SiLU, 8 elements/thread ----------------
__global__ void conv_silu8(const unsigned short* __restrict__ xzb, const float* __restrict__ cw,
                           unsigned short* __restrict__ xab) {
    size_t idx8 = ((size_t)blockIdx.x * 256 + threadIdx.x) * 8;   // m*2048 + e
    int e = (int)(idx8 & (EI - 1));
    size_t m = idx8 >> 11;
    int l = (int)(m & (LL - 1));
    u16x8 x0 = *(const u16x8*)(xzb + m * 4096 + e);
    u16x8 zer = {0,0,0,0,0,0,0,0};
    u16x8 x1 = (l >= 1) ? *(const u16x8*)(xzb + (m - 1) * 4096 + e) : zer;
    u16x8 x2 = (l >= 2) ? *(const u16x8*)(xzb + (m - 2) * 4096 + e) : zer;
    u16x8 x3 = (l >= 3) ? *(const u16x8*)(xzb + (m - 3) * 4096 + e) : zer;
    u16x8 o;
    #pragma unroll
    for (int j = 0; j < 8; ++j) {
        float4 wv = ((const float4*)cw)[e + j];
        float s = bf2f(x0[j]) * wv.w + bf2f(x1[j]) * wv.z
                + bf2f(x2[j]) * wv.y + bf2f(x3[j]) * wv.x;
        float a = s / (1.f + __expf(-s));
        o[j] = f2bf(a);
    }
    *(u16x8*)(xab + idx8) = o;
}

// ---------------- selective scan, 3-phase chunked — r3-measured-best config ----------------
// CHUNK=32, NCHUNK=32, fp32 P/H/h0, e-major layout P[((b*NC+c)*NS+n)*2048 + e],
// 16 states/thread, uniform-address float4 B/C loads.
__global__ void scan_phase1(const unsigned short* __restrict__ dbufb, const unsigned short* __restrict__ xu,
                            const float* __restrict__ bc, const float* __restrict__ A_log,
                            float* __restrict__ P, float* __restrict__ H) {
    int tid = threadIdx.x;
    int c = blockIdx.y, b = blockIdx.z;
    int e = blockIdx.x * 256 + tid;
    int mbase = b * LL + c * CHUNK;
    float A[NS], h[NS], p[NS];
    #pragma unroll
    for (int j = 0; j < NS; j += 4) {
        float4 a = *(const float4*)(A_log + (size_t)e * NS + j);
        A[j] = -expf(a.x); A[j+1] = -expf(a.y); A[j+2] = -expf(a.z); A[j+3] = -expf(a.w);
    }
    #pragma unroll
    for (int j = 0; j < NS; ++j) { h[j] = 0.f; p[j] = 1.f; }
    const unsigned short* dp = dbufb + (size_t)mbase * 2048 + e;
    const unsigned short* up = xu    + (size_t)mbase * 2048 + e;
    for (int t = 0; t < CHUNK; ++t) {
        float d = bf2f(dp[(size_t)t * 2048]);
        float u = bf2f(up[(size_t)t * 2048]);
        float du = d * u;
        const float4* bv = (const float4*)(bc + (size_t)(mbase + t) * 32);  // uniform addr
        #pragma unroll
        for (int q4 = 0; q4 < 4; ++q4) {
            float4 Bq = bv[q4];
            float Bj[4] = {Bq.x, Bq.y, Bq.z, Bq.w};
            #pragma unroll
            for (int k = 0; k < 4; ++k) {
                int j = q4 * 4 + k;
                float dA = __expf(d * A[j]);
                p[j] *= dA;
                h[j] = fmaf(dA, h[j], du * Bj[k]);
            }
        }
    }
    size_t base = ((size_t)(b * NCHUNK + c) * NS) * 2048 + e;
    #pragma unroll
    for (int j = 0; j < NS; ++j) {
        P[base + (size_t)j * 2048] = p[j];
        H[base + (size_t)j * 2048] = h[j];
    }
}

// phase2: one thread per (b,n,e); contiguous-e loads; compose 32 chunks -> h0 + hlast
__global__ void scan_phase2(const float* __restrict__ P, const float* __restrict__ H,
                            float* __restrict__ h0, float* __restrict__ hlast) {
    int id = blockIdx.x * 256 + threadIdx.x;
    int e = id & (EI - 1);
    int bn = id >> 11;
    int n = bn & (NS - 1), b = bn >> 4;
    float h = 0.f;
    #pragma unroll 4
    for (int c = 0; c < NCHUNK; ++c) {
        size_t ix = (((size_t)(b * NCHUNK + c) * NS) + n) * 2048 + e;
        h0[ix] = h;
        h = fmaf(P[ix], h, H[ix]);
    }
    hlast[(((size_t)b * EI + e) * NS) + n] = h;
}

// phase3: rescan with h0; full y in-thread; y*silu(z) -> bf16
__global__ void scan_phase3(const unsigned short* __restrict__ dbufb, const unsigned short* __restrict__ xu,
                            const unsigned short* __restrict__ xzb,
                            const float* __restrict__ bc, const float* __restrict__ A_log,
                            const float* __restrict__ Dp, const float* __restrict__ h0,
                            unsigned short* __restrict__ ybf) {
    int tid = threadIdx.x;
    int c = blockIdx.y, b = blockIdx.z;
    int e = blockIdx.x * 256 + tid;
    int mbase = b * LL + c * CHUNK;
    float A[NS], h[NS];
    #pragma unroll
    for (int j = 0; j < NS; j += 4) {
        float4 a = *(const float4*)(A_log + (size_t)e * NS + j);
        A[j] = -expf(a.x); A[j+1] = -expf(a.y); A[j+2] = -expf(a.z); A[j+3] = -expf(a.w);
    }
    size_t base = ((size_t)(b * NCHUNK + c) * NS) * 2048 + e;
    #pragma unroll
    for (int j = 0; j < NS; ++j) h[j] = h0[base + (size_t)j * 2048];
    float D = Dp[e];
    const unsigned short* dp = dbufb + (size_t)mbase * 2048 + e;
    const unsigned short* up = xu    + (size_t)mbase * 2048 + e;
    const unsigned short* zp = xzb   + (size_t)mbase * 4096 + 2048 + e;
    unsigned short* yp = ybf + (size_t)mbase * 2048 + e;
    for (int t = 0; t < CHUNK; ++t) {
        float d = bf2f(dp[(size_t)t * 2048]);
        float u = bf2f(up[(size_t)t * 2048]);
        float du = d * u;
        const float4* bv = (const float4*)(bc + (size_t)(mbase + t) * 32);  // uniform addr
        float y = 0.f;
        #pragma unroll
        for (int q4 = 0; q4 < 2; ++q4) {
            float4 Bq0 = bv[q4 * 2], Bq1 = bv[q4 * 2 + 1];
            float4 Cq0 = bv[4 + q4 * 2], Cq1 = bv[4 + q4 * 2 + 1];
            float Bj[8] = {Bq0.x, Bq0.y, Bq0.z, Bq0.w, Bq1.x, Bq1.y, Bq1.z, Bq1.w};
            float Cj[8] = {Cq0.x, Cq0.y, Cq0.z, Cq0.w, Cq1.x, Cq1.y, Cq1.z, Cq1.w};
            #pragma unroll
            for (int k = 0; k < 8; ++k) {
                int j = q4 * 8 + k;
                float dA = __expf(d * A[j]);
                h[j] = fmaf(dA, h[j], du * Bj[k]);
                y = fmaf(h[j], Cj[k], y);
            }
        }
        float z = bf2f(zp[(size_t)t * 4096]);
        float sil = z / (1.f + __expf(-z));
        float yt = fmaf(u, D, y);
        yp[(size_t)t * 2048] = f2bf(yt * sil);
    }
}

extern "C" void kernel_launch(void* const* d_in, const int* in_sizes, int n_in,
                              void* d_out, int out_size, void* d_ws, size_t ws_size,
                              hipStream_t stream) {
    (void)in_sizes; (void)n_in; (void)out_size; (void)ws_size;
    const float* hidden = (const float*)d_in[0];
    const float* norm_w = (const float*)d_in[1];
    const float* W_in   = (const float*)d_in[2];
    const float* conv_w = (const float*)d_in[3];
    const float* W_x    = (const float*)d_in[4];
    const float* W_dt   = (const float*)d_in[5];
    const float* b_dt   = (const float*)d_in[6];
    const float* A_log  = (const float*)d_in[7];
    const float* D_par  = (const float*)d_in[8];
    const float* W_out  = (const float*)d_in[9];
    float* out = (float*)d_out;
    char* ws = (char*)d_ws;
    const size_t MB = 1ull << 20;

    unsigned short* xzb      = (unsigned short*)(ws + 0);            // 32 MB bf16 (x_in|z)
    unsigned short* xact_bf  = (unsigned short*)(ws + 32 * MB);      // 16 MB
    unsigned short* xnorm_bf = (unsigned short*)(ws + 48 * MB);      //  8 MB
    unsigned short* wt_in    = (unsigned short*)(ws + 56 * MB);      //  8 MB
    unsigned short* wt_out   = (unsigned short*)(ws + 64 * MB);      //  4 MB
    unsigned short* wt_x     = (unsigned short*)(ws + 68 * MB);      // 512 KB (padded 96->128 rows)
    unsigned short* wt_dt    = (unsigned short*)(ws + 68 * MB + 512 * 1024);  // 256 KB
    unsigned short* dtlr     = (unsigned short*)(ws + 69 * MB);      // 512 KB
    float*          bc       = (float*)(ws + 69 * MB + 512 * 1024);  // 512 KB
    unsigned short* dbufb    = (unsigned short*)(ws + 70 * MB);      // 16 MB bf16 delta
    unsigned short* ybf      = (unsigned short*)(ws + 86 * MB);      // 16 MB
    float*          h0       = (float*)(ws + 102 * MB);              // 16 MB fp32
    float*          P        = (float*)(ws + 118 * MB);              // 16 MB fp32
    float*          Hb       = (float*)(ws + 134 * MB);              // 16 MB fp32  (150 MB total)
    float* Ppart = P;                    // 16 MB x-proj split-K fp32 partials (dead before phase1)
    unsigned short* Pout = (unsigned short*)P;  // 32 MB out-proj bf16 partials (P/Hb dead after phase2)
    float* hlast = out + (size_t)MM * DM;

    // pre-pass: all weight transposes + rmsnorm in one launch
    pre_all<<<10624, dim3(32, 8), 0, stream>>>(W_in, W_x, W_dt, W_out, hidden, norm_w,
                                               wt_in, wt_x, wt_dt, wt_out, xnorm_bf);
    // xzb = bf16( rmsnorm(x) @ W_in )   (M=4096, N=4096, K=1024)
    g_inproj<<<dim3(32, 32), 256, 0, stream>>>(xnorm_bf, wt_in, xzb, MM, 4096, 1024, 4096);
    // x_act = silu(dwconv(x_in))  (bf16)
    conv_silu8<<<(MM * EI) / (256 * 8), 256, 0, stream>>>(xzb, conv_w, xact_bf);
    // x_db partials = x_act @ W_x, split-K over 8 slices (M=4096, N=128pad, K=2048)
    g_xproj<<<dim3(8, 32), 256, 0, stream>>>(xact_bf, wt_x, Ppart, MM, 128, 2048, 128);
    xproj_reduce<<<(MM * 128) / 256, 256, 0, stream>>>(Ppart, dtlr, bc);
    // delta = bf16( softplus(dtlr @ W_dt + b_dt) )   (M=4096, N=2048, K=64)
    g_dtproj<<<dim3(16, 32), 256, 0, stream>>>(dtlr, wt_dt, b_dt, dbufb, MM, 2048, 64, 2048);
    // chunked selective scan, 3 phases (r3 config: CHUNK=32, fp32 P/H/h0, e-major)
    scan_phase1<<<dim3(8, NCHUNK, BB), 256, 0, stream>>>(dbufb, xact_bf, bc, A_log, P, Hb);
    scan_phase2<<<(BB * NS * EI) / 256, 256, 0, stream>>>(P, Hb, h0, hlast);
    scan_phase3<<<dim3(8, NCHUNK, BB), 256, 0, stream>>>(dbufb, xact_bf, xzb, bc, A_log, D_par,
                                                         h0, ybf);
    // out-proj split-K=4: partials = y @ W_out slices  (M=4096, N=1024, K=2048)
    g_outproj<<<dim3(8, 32, 4), 256, 0, stream>>>(ybf, wt_out, Pout, MM, 1024, 2048, 1024);
    // out = residual + sum partials
    outproj_reduce<<<(MM * DM / 4) / 256, 256, 0, stream>>>(Pout, hidden, out);
}